// Round 8
// baseline (26.412 us; speedup 1.0000x reference)
//
#include <hip/hip_runtime.h>

constexpr int   P     = 512;
constexpr int   W     = 256;
constexpr int   H     = 256;
constexpr float FXc   = 256.0f;
constexpr float FYc   = 256.0f;
constexpr float NEARc = 0.2f;
constexpr float BLUR  = 0.3f;
constexpr float LIMX  = 0.65f;
constexpr float LIMY  = 0.65f;

// d_out layout (floats)
constexpr int COLOR_OFF = 0;
constexpr int RADII_OFF = 196608;
constexpr int DEPTH_OFF = 197120;
constexpr int OPAC_OFF  = 262656;
constexpr int NT_OFF    = 328192;

// One block per row, 512 threads = 8 waves = 4 x-spans x 2 depth-segments.
// Prep: 1 gaussian/thread, row+screen-x cull, stable sort by (depth,orig).
// Waves 0-3 blend sorted ranks [0,nh) on x-span (wv&3); waves 4-7 blend
// [nh,n). Segment-1 partials combine exactly: color = a0 + T0*a1, T = T0*T1.
// n_touched for gaussians {2row, 2row+1} via exact bbox scan (keep() is
// independent of blending). Single graph node, no atomics to global.
__global__ __launch_bounds__(512) void fused_row_kernel(
    const float* __restrict__ means3D, const float* __restrict__ scales,
    const float* __restrict__ rots,    const float* __restrict__ opacs,
    const float* __restrict__ cols,    const float* __restrict__ vm,
    const float* __restrict__ pm,      const float* __restrict__ bg,
    float* __restrict__ out)
{
    __shared__ float4 g4u[P * 3];        // unsorted survivor records
    __shared__ float4 g4s[P * 3];        // depth-sorted survivor records
    __shared__ float  sdep[P];
    __shared__ int    sorig[P];
    __shared__ int    wlist[8][P + 1];   // per-wave compacted rank lists
    __shared__ float  part[5][W];        // segment-1 partials r,g,b,d,T
    __shared__ float4 ntrec[2][2];
    __shared__ int    s_cnt2[2];
    __shared__ int    s_n;

    const int tid  = threadIdx.x;
    const int row  = blockIdx.x;
    const int wv   = tid >> 6;
    const int lane = tid & 63;
    const float fy = (float)row;

    if (tid == 0) s_n = 0;
    if (tid < 2)  s_cnt2[tid] = 0;
    __syncthreads();

    // ---- prep: 1 gaussian per thread; row+screen-x cull into LDS ----
    {
        const int g = tid;

        const float mx = means3D[g*3+0], my = means3D[g*3+1], mz = means3D[g*3+2];

        const float pv0 = vm[0]*mx + vm[1]*my + vm[2]*mz  + vm[3];
        const float pv1 = vm[4]*mx + vm[5]*my + vm[6]*mz  + vm[7];
        const float pv2 = vm[8]*mx + vm[9]*my + vm[10]*mz + vm[11];
        const float depth = pv2;

        const float ph0 = pm[0]*mx  + pm[1]*my  + pm[2]*mz  + pm[3];
        const float ph1 = pm[4]*mx  + pm[5]*my  + pm[6]*mz  + pm[7];
        const float ph3 = pm[12]*mx + pm[13]*my + pm[14]*mz + pm[15];
        const float pwn = 1.0f / (ph3 + 1e-7f);
        const float pp0 = ph0 * pwn, pp1 = ph1 * pwn;

        float q0 = rots[g*4+0], q1 = rots[g*4+1], q2 = rots[g*4+2], q3 = rots[g*4+3];
        const float qinv = 1.0f / sqrtf(q0*q0 + q1*q1 + q2*q2 + q3*q3);
        q0 *= qinv; q1 *= qinv; q2 *= qinv; q3 *= qinv;
        const float r = q0, x = q1, y = q2, z = q3;
        const float R00 = 1.f - 2.f*(y*y + z*z), R01 = 2.f*(x*y - r*z), R02 = 2.f*(x*z + r*y);
        const float R10 = 2.f*(x*y + r*z), R11 = 1.f - 2.f*(x*x + z*z), R12 = 2.f*(y*z - r*x);
        const float R20 = 2.f*(x*z - r*y), R21 = 2.f*(y*z + r*x), R22 = 1.f - 2.f*(x*x + y*y);

        const float s0 = scales[g*3+0], s1 = scales[g*3+1], s2 = scales[g*3+2];
        const float M00 = R00*s0, M01 = R01*s1, M02 = R02*s2;
        const float M10 = R10*s0, M11 = R11*s1, M12 = R12*s2;
        const float M20 = R20*s0, M21 = R21*s1, M22 = R22*s2;
        const float c00 = M00*M00 + M01*M01 + M02*M02;
        const float c01 = M00*M10 + M01*M11 + M02*M12;
        const float c02 = M00*M20 + M01*M21 + M02*M22;
        const float c11 = M10*M10 + M11*M11 + M12*M12;
        const float c12 = M10*M20 + M11*M21 + M12*M22;
        const float c22 = M20*M20 + M21*M21 + M22*M22;

        const float tz  = (fabsf(depth) < 1e-6f) ? 1e-6f : depth;
        const float txc = fminf(fmaxf(pv0 / tz, -LIMX), LIMX) * tz;
        const float tyc = fminf(fmaxf(pv1 / tz, -LIMY), LIMY) * tz;

        const float J00 = FXc / tz, J02 = -FXc * txc / (tz*tz);
        const float J11 = FYc / tz, J12 = -FYc * tyc / (tz*tz);

        const float T00 = J00*vm[0] + J02*vm[8];
        const float T01 = J00*vm[1] + J02*vm[9];
        const float T02 = J00*vm[2] + J02*vm[10];
        const float T10 = J11*vm[4] + J12*vm[8];
        const float T11 = J11*vm[5] + J12*vm[9];
        const float T12 = J11*vm[6] + J12*vm[10];

        const float V00 = T00*c00 + T01*c01 + T02*c02;
        const float V01 = T00*c01 + T01*c11 + T02*c12;
        const float V02 = T00*c02 + T01*c12 + T02*c22;
        const float V10 = T10*c00 + T11*c01 + T12*c02;
        const float V11 = T10*c01 + T11*c11 + T12*c12;
        const float V12 = T10*c02 + T11*c12 + T12*c22;

        const float a = V00*T00 + V01*T01 + V02*T02 + BLUR;
        const float b = V00*T10 + V01*T11 + V02*T12;
        const float c = V10*T10 + V11*T11 + V12*T12 + BLUR;
        const float det = a*c - b*b;

        const bool  valid = (depth > NEARc) && (det > 0.0f);
        const float det_s = valid ? det : 1.0f;
        const float conic_a =  c / det_s;
        const float conic_b = -b / det_s;
        const float conic_c =  a / det_s;

        const float op = opacs[g];
        const float L  = logf(255.0f * op);          // keep needs power >= -L
        const float rowrad2 = valid ? (2.0f * c * L) * 1.0001f + 1e-4f : -1.0f;
        const float xrad2   = valid ? (2.0f * a * L) * 1.0001f + 1e-4f : -1.0f;

        if (row == 0) {
            const float mid = 0.5f * (a + c);
            const float lam = mid + sqrtf(fmaxf(mid*mid - det, 0.1f));
            out[RADII_OFF + g] = valid ? ceilf(3.0f * sqrtf(lam)) : 0.0f;
        }

        const float px = ((pp0 + 1.0f) * (float)W - 1.0f) * 0.5f;
        const float py = ((pp1 + 1.0f) * (float)H - 1.0f) * 0.5f;

        // stash params for this block's two n_touched gaussians
        if ((g >> 1) == row) {
            const int e = g & 1;
            ntrec[e][0] = make_float4(px, py, -0.5f * conic_a, -conic_b);
            ntrec[e][1] = make_float4(-0.5f * conic_c, op, xrad2, rowrad2);
        }

        const float dyv = py - fy;
        const float dxm = fmaxf(0.0f, fmaxf(-px, px - 255.0f));
        if (dyv * dyv <= rowrad2 && dxm * dxm <= xrad2) {
            const int s = atomicAdd(&s_n, 1);
            g4u[s*3+0] = make_float4(py, -conic_b, px, -0.5f * conic_a);
            g4u[s*3+1] = make_float4(-0.5f * conic_c, op, depth, xrad2);
            g4u[s*3+2] = make_float4(cols[g*3+0], cols[g*3+1], cols[g*3+2], 0.0f);
            sdep[s]  = depth;
            sorig[s] = g;
        }
    }
    __syncthreads();
    const int n  = s_n;
    const int nh = (n + 1) >> 1;

    // ---- stable rank-sort by (depth, orig); scatter into g4s ----
    for (int t = tid; t < n; t += 512) {
        const float d = sdep[t];
        const int   o = sorig[t];
        int rank = 0;
        for (int j = 0; j < n; ++j) {
            const float dj = sdep[j];
            rank += (dj < d) || (dj == d && sorig[j] < o);
        }
        g4s[rank*3+0] = g4u[t*3+0];
        g4s[rank*3+1] = g4u[t*3+1];
        g4s[rank*3+2] = g4u[t*3+2];
    }
    __syncthreads();

    // ---- per-wave (x-span, segment) compaction, order-preserving ----
    const int seg  = wv >> 2;
    const int xsp  = wv & 3;
    const int rbeg = seg ? nh : 0;
    const int rend = seg ? n  : nh;
    const float wx0 = (float)(xsp * 64);
    const float wx1 = wx0 + 63.0f;
    int cnt = 0;
    for (int tb = rbeg; tb < rend; tb += 64) {
        const int t = tb + lane;
        bool take = false;
        if (t < rend) {
            const float pxg = g4s[t*3+0].z;
            const float xr2 = g4s[t*3+1].w;
            const float dm  = fmaxf(0.0f, fmaxf(wx0 - pxg, pxg - wx1));
            take = (dm * dm <= xr2);
        }
        const unsigned long long mk = __ballot(take);
        if (take)
            wlist[wv][cnt + __popcll(mk & ((1ull << lane) - 1ull))] = t;
        cnt += __popcll(mk);
    }
    if (lane == 0) wlist[wv][cnt] = (cnt > 0) ? wlist[wv][cnt - 1] : 0;

    // ---- branchless blend with register prefetch (this wave's list) ----
    const int   xpix = xsp * 64 + lane;
    const float fx = (float)xpix;
    float T = 1.0f, ar = 0.f, ag = 0.f, ab = 0.f, ad = 0.f;

    if (cnt > 0) {
        int jc = wlist[wv][0];
        float4 h  = g4s[jc*3+0];
        float4 mm = g4s[jc*3+1];
        float4 cl = g4s[jc*3+2];
        for (int t = 0; t < cnt; ++t) {
            const int jn = wlist[wv][t + 1];
            const float4 hn  = g4s[jn*3+0];
            const float4 mmn = g4s[jn*3+1];
            const float4 cln = g4s[jn*3+2];

            const float dx = h.z - fx;
            const float dy = h.x - fy;
            const float pw = fmaf(h.w, dx*dx, fmaf(mm.x, dy*dy, h.y * dx * dy));
            const float alpha = fminf(0.99f, mm.y * __expf(pw));
            const bool keep = (pw <= 0.0f) && (alpha >= (1.0f / 255.0f));

            const float ae  = keep ? alpha : 0.0f;
            const float wgt = ae * T;
            ar = fmaf(wgt, cl.x, ar); ag = fmaf(wgt, cl.y, ag);
            ab = fmaf(wgt, cl.z, ab); ad = fmaf(wgt, mm.z, ad);
            T  = fmaf(-ae, T, T);

            h = hn; mm = mmn; cl = cln;
        }
    }

    // ---- segment combine: color = a0 + T0*a1, T = T0*T1 (exact) ----
    if (seg == 1) {
        part[0][xpix] = ar; part[1][xpix] = ag; part[2][xpix] = ab;
        part[3][xpix] = ad; part[4][xpix] = T;
    }
    __syncthreads();
    if (seg == 0) {
        const float r1 = part[0][xpix], g1 = part[1][xpix], b1 = part[2][xpix];
        const float d1 = part[3][xpix], T1 = part[4][xpix];
        const float fr = fmaf(T, r1, ar);
        const float fg = fmaf(T, g1, ag);
        const float fb = fmaf(T, b1, ab);
        const float fd = fmaf(T, d1, ad);
        const float fT = T * T1;

        const int pix = row * W + xpix;
        out[COLOR_OFF + 0*65536 + pix] = fr + fT * bg[0];
        out[COLOR_OFF + 1*65536 + pix] = fg + fT * bg[1];
        out[COLOR_OFF + 2*65536 + pix] = fb + fT * bg[2];
        out[DEPTH_OFF + pix]           = fd;
        out[OPAC_OFF  + pix]           = 1.0f - fT;
    }

    // ---- exact n_touched for gaussians 2*row, 2*row+1 via bbox scan ----
    #pragma unroll
    for (int e = 0; e < 2; ++e) {
        const float4 r0 = ntrec[e][0], r1 = ntrec[e][1];
        const float pxg = r0.x, pyg = r0.y, pa = r0.z, pb = r0.w;
        const float pc = r1.x, opg = r1.y, rx2 = r1.z, ry2 = r1.w;
        int cc2 = 0;
        if (ry2 > 0.0f && rx2 > 0.0f) {
            const float ry = sqrtf(ry2), rx = sqrtf(rx2);
            const int y0 = max(0, (int)ceilf(pyg - ry));
            const int y1 = min(H - 1, (int)floorf(pyg + ry));
            const int x0 = max(0, (int)ceilf(pxg - rx));
            const int x1 = min(W - 1, (int)floorf(pxg + rx));
            const int xx = x0 + tid;
            if (xx <= x1 && y0 <= y1) {
                const float dx = (float)xx - pxg;
                const float padx2 = pa * dx * dx;
                for (int yy = y0; yy <= y1; ++yy) {
                    const float dy = (float)yy - pyg;
                    const float pw = fmaf(pc, dy*dy, fmaf(pb, dx*dy, padx2));
                    const float alpha = fminf(0.99f, opg * __expf(pw));
                    cc2 += (pw <= 0.0f) && (alpha >= (1.0f / 255.0f));
                }
            }
        }
        #pragma unroll
        for (int off = 32; off; off >>= 1) cc2 += __shfl_down(cc2, off);
        if (lane == 0 && cc2) atomicAdd(&s_cnt2[e], cc2);
    }
    __syncthreads();
    if (tid < 2) out[NT_OFF + (row << 1) + tid] = (float)s_cnt2[tid];
}

extern "C" void kernel_launch(void* const* d_in, const int* in_sizes, int n_in,
                              void* d_out, int out_size, void* d_ws, size_t ws_size,
                              hipStream_t stream) {
    const float* means3D = (const float*)d_in[0];
    const float* scales  = (const float*)d_in[1];
    const float* rots    = (const float*)d_in[2];
    const float* opacs   = (const float*)d_in[3];
    const float* cols    = (const float*)d_in[4];
    const float* vm      = (const float*)d_in[5];
    const float* pm      = (const float*)d_in[6];
    const float* bg      = (const float*)d_in[8];
    float* out = (float*)d_out;

    fused_row_kernel<<<H, 512, 0, stream>>>(means3D, scales, rots, opacs, cols,
                                            vm, pm, bg, out);
}

// Round 9
// 21.656 us; speedup vs baseline: 1.2196x; 1.2196x over previous
//
#include <hip/hip_runtime.h>

constexpr int   P     = 512;
constexpr int   W     = 256;
constexpr int   H     = 256;
constexpr float FXc   = 256.0f;
constexpr float FYc   = 256.0f;
constexpr float NEARc = 0.2f;
constexpr float BLUR  = 0.3f;
constexpr float LIMX  = 0.65f;
constexpr float LIMY  = 0.65f;

// d_out layout (floats)
constexpr int COLOR_OFF = 0;
constexpr int RADII_OFF = 196608;
constexpr int DEPTH_OFF = 197120;
constexpr int OPAC_OFF  = 262656;
constexpr int NT_OFF    = 328192;

// 512 blocks: block b = (row = b>>1, xhalf = b&1) covers 128 pixels.
// 256 threads = 4 waves = 2 x-spans (64 px) x 2 depth segments.
// Per block: prep all 512 gaussians (2/thread), cull to row+x-half range,
// stable sort survivors by (depth, orig), per-wave (span, segment)
// compaction, prefetched branchless blend, exact LDS segment combine
// (color = a0 + T0*a1, T = T0*T1). Block b also computes n_touched[b]
// via an exact bbox scan (keep() is independent of blending).
// Single graph node, no global atomics, deterministic.
__global__ __launch_bounds__(256) void fused_half_kernel(
    const float* __restrict__ means3D, const float* __restrict__ scales,
    const float* __restrict__ rots,    const float* __restrict__ opacs,
    const float* __restrict__ cols,    const float* __restrict__ vm,
    const float* __restrict__ pm,      const float* __restrict__ bg,
    float* __restrict__ out)
{
    __shared__ float4 g4u[P * 3];        // unsorted survivor records
    __shared__ float4 g4s[P * 3];        // depth-sorted survivor records
    __shared__ float  sdep[P];
    __shared__ int    sorig[P];
    __shared__ int    wlist[4][P + 1];   // per-wave compacted rank lists
    __shared__ float  part[5][128];      // segment-1 partials r,g,b,d,T
    __shared__ float4 ntrec[2];          // bbox-scan params of gaussian b
    __shared__ int    s_cnt;
    __shared__ int    s_n;

    const int tid   = threadIdx.x;
    const int bid   = blockIdx.x;
    const int row   = bid >> 1;
    const int xbase = (bid & 1) * 128;
    const int wv    = tid >> 6;
    const int lane  = tid & 63;
    const float fy  = (float)row;

    if (tid == 0) { s_n = 0; s_cnt = 0; }
    __syncthreads();

    // ---- prep 2 gaussians/thread; cull to (row, x-half) into LDS ----
    #pragma unroll
    for (int k = 0; k < 2; ++k) {
        const int g = tid + k * 256;

        const float mx = means3D[g*3+0], my = means3D[g*3+1], mz = means3D[g*3+2];

        const float pv0 = vm[0]*mx + vm[1]*my + vm[2]*mz  + vm[3];
        const float pv1 = vm[4]*mx + vm[5]*my + vm[6]*mz  + vm[7];
        const float pv2 = vm[8]*mx + vm[9]*my + vm[10]*mz + vm[11];
        const float depth = pv2;

        const float ph0 = pm[0]*mx  + pm[1]*my  + pm[2]*mz  + pm[3];
        const float ph1 = pm[4]*mx  + pm[5]*my  + pm[6]*mz  + pm[7];
        const float ph3 = pm[12]*mx + pm[13]*my + pm[14]*mz + pm[15];
        const float pwn = 1.0f / (ph3 + 1e-7f);
        const float pp0 = ph0 * pwn, pp1 = ph1 * pwn;

        float q0 = rots[g*4+0], q1 = rots[g*4+1], q2 = rots[g*4+2], q3 = rots[g*4+3];
        const float qinv = 1.0f / sqrtf(q0*q0 + q1*q1 + q2*q2 + q3*q3);
        q0 *= qinv; q1 *= qinv; q2 *= qinv; q3 *= qinv;
        const float r = q0, x = q1, y = q2, z = q3;
        const float R00 = 1.f - 2.f*(y*y + z*z), R01 = 2.f*(x*y - r*z), R02 = 2.f*(x*z + r*y);
        const float R10 = 2.f*(x*y + r*z), R11 = 1.f - 2.f*(x*x + z*z), R12 = 2.f*(y*z - r*x);
        const float R20 = 2.f*(x*z - r*y), R21 = 2.f*(y*z + r*x), R22 = 1.f - 2.f*(x*x + y*y);

        const float s0 = scales[g*3+0], s1 = scales[g*3+1], s2 = scales[g*3+2];
        const float M00 = R00*s0, M01 = R01*s1, M02 = R02*s2;
        const float M10 = R10*s0, M11 = R11*s1, M12 = R12*s2;
        const float M20 = R20*s0, M21 = R21*s1, M22 = R22*s2;
        const float c00 = M00*M00 + M01*M01 + M02*M02;
        const float c01 = M00*M10 + M01*M11 + M02*M12;
        const float c02 = M00*M20 + M01*M21 + M02*M22;
        const float c11 = M10*M10 + M11*M11 + M12*M12;
        const float c12 = M10*M20 + M11*M21 + M12*M22;
        const float c22 = M20*M20 + M21*M21 + M22*M22;

        const float tz  = (fabsf(depth) < 1e-6f) ? 1e-6f : depth;
        const float txc = fminf(fmaxf(pv0 / tz, -LIMX), LIMX) * tz;
        const float tyc = fminf(fmaxf(pv1 / tz, -LIMY), LIMY) * tz;

        const float J00 = FXc / tz, J02 = -FXc * txc / (tz*tz);
        const float J11 = FYc / tz, J12 = -FYc * tyc / (tz*tz);

        const float T00 = J00*vm[0] + J02*vm[8];
        const float T01 = J00*vm[1] + J02*vm[9];
        const float T02 = J00*vm[2] + J02*vm[10];
        const float T10 = J11*vm[4] + J12*vm[8];
        const float T11 = J11*vm[5] + J12*vm[9];
        const float T12 = J11*vm[6] + J12*vm[10];

        const float V00 = T00*c00 + T01*c01 + T02*c02;
        const float V01 = T00*c01 + T01*c11 + T02*c12;
        const float V02 = T00*c02 + T01*c12 + T02*c22;
        const float V10 = T10*c00 + T11*c01 + T12*c02;
        const float V11 = T10*c01 + T11*c11 + T12*c12;
        const float V12 = T10*c02 + T11*c12 + T12*c22;

        const float a = V00*T00 + V01*T01 + V02*T02 + BLUR;
        const float b = V00*T10 + V01*T11 + V02*T12;
        const float c = V10*T10 + V11*T11 + V12*T12 + BLUR;
        const float det = a*c - b*b;

        const bool  valid = (depth > NEARc) && (det > 0.0f);
        const float det_s = valid ? det : 1.0f;
        const float conic_a =  c / det_s;
        const float conic_b = -b / det_s;
        const float conic_c =  a / det_s;

        const float op = opacs[g];
        const float L  = logf(255.0f * op);          // keep needs power >= -L
        const float rowrad2 = valid ? (2.0f * c * L) * 1.0001f + 1e-4f : -1.0f;
        const float xrad2   = valid ? (2.0f * a * L) * 1.0001f + 1e-4f : -1.0f;

        if (bid == 0) {
            const float mid = 0.5f * (a + c);
            const float lam = mid + sqrtf(fmaxf(mid*mid - det, 0.1f));
            out[RADII_OFF + g] = valid ? ceilf(3.0f * sqrtf(lam)) : 0.0f;
        }

        const float px = ((pp0 + 1.0f) * (float)W - 1.0f) * 0.5f;
        const float py = ((pp1 + 1.0f) * (float)H - 1.0f) * 0.5f;

        // stash bbox-scan params for this block's n_touched gaussian (g == bid)
        if (g == bid) {
            ntrec[0] = make_float4(px, py, -0.5f * conic_a, -conic_b);
            ntrec[1] = make_float4(-0.5f * conic_c, op, xrad2, rowrad2);
        }

        const float dyv = py - fy;
        const float dxm = fmaxf(0.0f, fmaxf((float)xbase - px,
                                            px - (float)(xbase + 127)));
        if (dyv * dyv <= rowrad2 && dxm * dxm <= xrad2) {
            const int s = atomicAdd(&s_n, 1);
            g4u[s*3+0] = make_float4(py, -conic_b, px, -0.5f * conic_a);
            g4u[s*3+1] = make_float4(-0.5f * conic_c, op, depth, xrad2);
            g4u[s*3+2] = make_float4(cols[g*3+0], cols[g*3+1], cols[g*3+2], 0.0f);
            sdep[s]  = depth;
            sorig[s] = g;
        }
    }
    __syncthreads();
    const int n  = s_n;
    const int nh = (n + 1) >> 1;

    // ---- stable rank-sort by (depth, orig); scatter into g4s ----
    for (int t = tid; t < n; t += 256) {
        const float d = sdep[t];
        const int   o = sorig[t];
        int rank = 0;
        for (int j = 0; j < n; ++j) {
            const float dj = sdep[j];
            rank += (dj < d) || (dj == d && sorig[j] < o);
        }
        g4s[rank*3+0] = g4u[t*3+0];
        g4s[rank*3+1] = g4u[t*3+1];
        g4s[rank*3+2] = g4u[t*3+2];
    }
    __syncthreads();

    // ---- per-wave (x-span, segment) compaction, order-preserving ----
    const int seg  = wv >> 1;
    const int xsp  = wv & 1;
    const int rbeg = seg ? nh : 0;
    const int rend = seg ? n  : nh;
    const float wx0 = (float)(xbase + xsp * 64);
    const float wx1 = wx0 + 63.0f;
    int cnt = 0;
    for (int tb = rbeg; tb < rend; tb += 64) {
        const int t = tb + lane;
        bool take = false;
        if (t < rend) {
            const float pxg = g4s[t*3+0].z;
            const float xr2 = g4s[t*3+1].w;
            const float dm  = fmaxf(0.0f, fmaxf(wx0 - pxg, pxg - wx1));
            take = (dm * dm <= xr2);
        }
        const unsigned long long mk = __ballot(take);
        if (take)
            wlist[wv][cnt + __popcll(mk & ((1ull << lane) - 1ull))] = t;
        cnt += __popcll(mk);
    }
    if (lane == 0) wlist[wv][cnt] = (cnt > 0) ? wlist[wv][cnt - 1] : 0;

    // ---- branchless blend with register prefetch (this wave's list) ----
    const int   xloc = xsp * 64 + lane;          // 0..127 within block
    const float fx   = (float)(xbase + xloc);
    float T = 1.0f, ar = 0.f, ag = 0.f, ab = 0.f, ad = 0.f;

    if (cnt > 0) {
        float4 h, mm, cl;
        {
            const int jc = wlist[wv][0];
            h  = g4s[jc*3+0]; mm = g4s[jc*3+1]; cl = g4s[jc*3+2];
        }
        for (int t = 0; t < cnt; ++t) {
            const int jn = wlist[wv][t + 1];
            const float4 hn  = g4s[jn*3+0];
            const float4 mmn = g4s[jn*3+1];
            const float4 cln = g4s[jn*3+2];

            const float dx = h.z - fx;
            const float dy = h.x - fy;
            const float pw = fmaf(h.w, dx*dx, fmaf(mm.x, dy*dy, h.y * dx * dy));
            const float alpha = fminf(0.99f, mm.y * __expf(pw));
            const bool keep = (pw <= 0.0f) && (alpha >= (1.0f / 255.0f));

            const float ae  = keep ? alpha : 0.0f;
            const float wgt = ae * T;
            ar = fmaf(wgt, cl.x, ar); ag = fmaf(wgt, cl.y, ag);
            ab = fmaf(wgt, cl.z, ab); ad = fmaf(wgt, mm.z, ad);
            T  = fmaf(-ae, T, T);

            h = hn; mm = mmn; cl = cln;
        }
    }

    // ---- segment combine: color = a0 + T0*a1, T = T0*T1 (exact) ----
    if (seg == 1) {
        part[0][xloc] = ar; part[1][xloc] = ag; part[2][xloc] = ab;
        part[3][xloc] = ad; part[4][xloc] = T;
    }
    __syncthreads();
    if (seg == 0) {
        const float r1 = part[0][xloc], g1 = part[1][xloc], b1 = part[2][xloc];
        const float d1 = part[3][xloc], T1 = part[4][xloc];
        const float fr = fmaf(T, r1, ar);
        const float fg = fmaf(T, g1, ag);
        const float fb = fmaf(T, b1, ab);
        const float fd = fmaf(T, d1, ad);
        const float fT = T * T1;

        const int pix = row * W + xbase + xloc;
        out[COLOR_OFF + 0*65536 + pix] = fr + fT * bg[0];
        out[COLOR_OFF + 1*65536 + pix] = fg + fT * bg[1];
        out[COLOR_OFF + 2*65536 + pix] = fb + fT * bg[2];
        out[DEPTH_OFF + pix]           = fd;
        out[OPAC_OFF  + pix]           = 1.0f - fT;
    }

    // ---- exact n_touched for gaussian `bid` via bbox scan ----
    {
        const float4 r0 = ntrec[0], r1 = ntrec[1];
        const float pxg = r0.x, pyg = r0.y, pa = r0.z, pb = r0.w;
        const float pc = r1.x, opg = r1.y, rx2 = r1.z, ry2 = r1.w;
        int cc2 = 0;
        if (ry2 > 0.0f && rx2 > 0.0f) {
            const float ry = sqrtf(ry2), rx = sqrtf(rx2);
            const int y0 = max(0, (int)ceilf(pyg - ry));
            const int y1 = min(H - 1, (int)floorf(pyg + ry));
            const int x0 = max(0, (int)ceilf(pxg - rx));
            const int x1 = min(W - 1, (int)floorf(pxg + rx));
            const int xx = x0 + tid;
            if (xx <= x1 && y0 <= y1) {
                const float dx = (float)xx - pxg;
                const float padx2 = pa * dx * dx;
                for (int yy = y0; yy <= y1; ++yy) {
                    const float dy = (float)yy - pyg;
                    const float pw = fmaf(pc, dy*dy, fmaf(pb, dx*dy, padx2));
                    const float alpha = fminf(0.99f, opg * __expf(pw));
                    cc2 += (pw <= 0.0f) && (alpha >= (1.0f / 255.0f));
                }
            }
        }
        #pragma unroll
        for (int off = 32; off; off >>= 1) cc2 += __shfl_down(cc2, off);
        if (lane == 0 && cc2) atomicAdd(&s_cnt, cc2);
    }
    __syncthreads();
    if (tid == 0) out[NT_OFF + bid] = (float)s_cnt;
}

extern "C" void kernel_launch(void* const* d_in, const int* in_sizes, int n_in,
                              void* d_out, int out_size, void* d_ws, size_t ws_size,
                              hipStream_t stream) {
    const float* means3D = (const float*)d_in[0];
    const float* scales  = (const float*)d_in[1];
    const float* rots    = (const float*)d_in[2];
    const float* opacs   = (const float*)d_in[3];
    const float* cols    = (const float*)d_in[4];
    const float* vm      = (const float*)d_in[5];
    const float* pm      = (const float*)d_in[6];
    const float* bg      = (const float*)d_in[8];
    float* out = (float*)d_out;

    fused_half_kernel<<<2 * H, 256, 0, stream>>>(means3D, scales, rots, opacs,
                                                 cols, vm, pm, bg, out);
}

// Round 10
// 20.566 us; speedup vs baseline: 1.2842x; 1.0530x over previous
//
#include <hip/hip_runtime.h>

constexpr int   P     = 512;
constexpr int   W     = 256;
constexpr int   H     = 256;
constexpr float FXc   = 256.0f;
constexpr float FYc   = 256.0f;
constexpr float NEARc = 0.2f;
constexpr float BLUR  = 0.3f;
constexpr float LIMX  = 0.65f;
constexpr float LIMY  = 0.65f;

// d_out layout (floats)
constexpr int COLOR_OFF = 0;
constexpr int RADII_OFF = 196608;
constexpr int DEPTH_OFF = 197120;
constexpr int OPAC_OFF  = 262656;
constexpr int NT_OFF    = 328192;

// 1024 blocks: b = (row = b>>2, xq = b&3) covers 64 pixels; 4 blocks/CU
// co-resident (LDS ~34.6 KB, __launch_bounds__(256,4)). 256 threads =
// 4 waves = 4 depth-quarters of this window's sorted survivor list; lane =
// pixel. Prep culls all 512 gaussians directly to the 64-px window, rank
// permutation (no physical sort), blend via rank2slot indirection with
// register prefetch, exact 4-way LDS combine:
//   final = a0 + T0*(a1 + T1*(a2 + T2*a3)), T = T0*T1*T2*T3.
// Blocks 0..511 also compute n_touched[bid] via exact bbox scan (keep() is
// independent of blending). Single graph node, no global atomics.
__global__ __launch_bounds__(256, 4) void fused_q_kernel(
    const float* __restrict__ means3D, const float* __restrict__ scales,
    const float* __restrict__ rots,    const float* __restrict__ opacs,
    const float* __restrict__ cols,    const float* __restrict__ vm,
    const float* __restrict__ pm,      const float* __restrict__ bg,
    float* __restrict__ out)
{
    __shared__ float4 g4u[P * 3];        // survivor records, slot order
    __shared__ float  sdep[P];
    __shared__ int    sorig[P];
    __shared__ int    rank2slot[P + 1];
    __shared__ float  part[3][5][64];    // waves 1..3 partials r,g,b,d,T
    __shared__ float4 ntrec[2];
    __shared__ int    s_cnt;
    __shared__ int    s_n;

    const int tid   = threadIdx.x;
    const int bid   = blockIdx.x;
    const int row   = bid >> 2;
    const int xbase = (bid & 3) * 64;
    const int wv    = tid >> 6;
    const int lane  = tid & 63;
    const float fy  = (float)row;

    if (tid == 0) { s_n = 0; s_cnt = 0; }
    __syncthreads();

    // ---- prep 2 gaussians/thread; cull to (row, 64-px window) ----
    #pragma unroll
    for (int k = 0; k < 2; ++k) {
        const int g = tid + k * 256;

        const float mx = means3D[g*3+0], my = means3D[g*3+1], mz = means3D[g*3+2];

        const float pv0 = vm[0]*mx + vm[1]*my + vm[2]*mz  + vm[3];
        const float pv1 = vm[4]*mx + vm[5]*my + vm[6]*mz  + vm[7];
        const float pv2 = vm[8]*mx + vm[9]*my + vm[10]*mz + vm[11];
        const float depth = pv2;

        const float ph0 = pm[0]*mx  + pm[1]*my  + pm[2]*mz  + pm[3];
        const float ph1 = pm[4]*mx  + pm[5]*my  + pm[6]*mz  + pm[7];
        const float ph3 = pm[12]*mx + pm[13]*my + pm[14]*mz + pm[15];
        const float pwn = 1.0f / (ph3 + 1e-7f);
        const float pp0 = ph0 * pwn, pp1 = ph1 * pwn;

        float q0 = rots[g*4+0], q1 = rots[g*4+1], q2 = rots[g*4+2], q3 = rots[g*4+3];
        const float qinv = 1.0f / sqrtf(q0*q0 + q1*q1 + q2*q2 + q3*q3);
        q0 *= qinv; q1 *= qinv; q2 *= qinv; q3 *= qinv;
        const float r = q0, x = q1, y = q2, z = q3;
        const float R00 = 1.f - 2.f*(y*y + z*z), R01 = 2.f*(x*y - r*z), R02 = 2.f*(x*z + r*y);
        const float R10 = 2.f*(x*y + r*z), R11 = 1.f - 2.f*(x*x + z*z), R12 = 2.f*(y*z - r*x);
        const float R20 = 2.f*(x*z - r*y), R21 = 2.f*(y*z + r*x), R22 = 1.f - 2.f*(x*x + y*y);

        const float s0 = scales[g*3+0], s1 = scales[g*3+1], s2 = scales[g*3+2];
        const float M00 = R00*s0, M01 = R01*s1, M02 = R02*s2;
        const float M10 = R10*s0, M11 = R11*s1, M12 = R12*s2;
        const float M20 = R20*s0, M21 = R21*s1, M22 = R22*s2;
        const float c00 = M00*M00 + M01*M01 + M02*M02;
        const float c01 = M00*M10 + M01*M11 + M02*M12;
        const float c02 = M00*M20 + M01*M21 + M02*M22;
        const float c11 = M10*M10 + M11*M11 + M12*M12;
        const float c12 = M10*M20 + M11*M21 + M12*M22;
        const float c22 = M20*M20 + M21*M21 + M22*M22;

        const float tz  = (fabsf(depth) < 1e-6f) ? 1e-6f : depth;
        const float txc = fminf(fmaxf(pv0 / tz, -LIMX), LIMX) * tz;
        const float tyc = fminf(fmaxf(pv1 / tz, -LIMY), LIMY) * tz;

        const float J00 = FXc / tz, J02 = -FXc * txc / (tz*tz);
        const float J11 = FYc / tz, J12 = -FYc * tyc / (tz*tz);

        const float T00 = J00*vm[0] + J02*vm[8];
        const float T01 = J00*vm[1] + J02*vm[9];
        const float T02 = J00*vm[2] + J02*vm[10];
        const float T10 = J11*vm[4] + J12*vm[8];
        const float T11 = J11*vm[5] + J12*vm[9];
        const float T12 = J11*vm[6] + J12*vm[10];

        const float V00 = T00*c00 + T01*c01 + T02*c02;
        const float V01 = T00*c01 + T01*c11 + T02*c12;
        const float V02 = T00*c02 + T01*c12 + T02*c22;
        const float V10 = T10*c00 + T11*c01 + T12*c02;
        const float V11 = T10*c01 + T11*c11 + T12*c12;
        const float V12 = T10*c02 + T11*c12 + T12*c22;

        const float a = V00*T00 + V01*T01 + V02*T02 + BLUR;
        const float b = V00*T10 + V01*T11 + V02*T12;
        const float c = V10*T10 + V11*T11 + V12*T12 + BLUR;
        const float det = a*c - b*b;

        const bool  valid = (depth > NEARc) && (det > 0.0f);
        const float det_s = valid ? det : 1.0f;
        const float conic_a =  c / det_s;
        const float conic_b = -b / det_s;
        const float conic_c =  a / det_s;

        const float op = opacs[g];
        const float L  = logf(255.0f * op);          // keep needs power >= -L
        const float rowrad2 = valid ? (2.0f * c * L) * 1.0001f + 1e-4f : -1.0f;
        const float xrad2   = valid ? (2.0f * a * L) * 1.0001f + 1e-4f : -1.0f;

        if (bid == 0) {
            const float mid = 0.5f * (a + c);
            const float lam = mid + sqrtf(fmaxf(mid*mid - det, 0.1f));
            out[RADII_OFF + g] = valid ? ceilf(3.0f * sqrtf(lam)) : 0.0f;
        }

        const float px = ((pp0 + 1.0f) * (float)W - 1.0f) * 0.5f;
        const float py = ((pp1 + 1.0f) * (float)H - 1.0f) * 0.5f;

        // stash bbox-scan params for this block's n_touched gaussian
        if (g == bid) {
            ntrec[0] = make_float4(px, py, -0.5f * conic_a, -conic_b);
            ntrec[1] = make_float4(-0.5f * conic_c, op, xrad2, rowrad2);
        }

        const float dyv = py - fy;
        const float dxm = fmaxf(0.0f, fmaxf((float)xbase - px,
                                            px - (float)(xbase + 63)));
        if (dyv * dyv <= rowrad2 && dxm * dxm <= xrad2) {
            const int s = atomicAdd(&s_n, 1);
            g4u[s*3+0] = make_float4(py, -conic_b, px, -0.5f * conic_a);
            g4u[s*3+1] = make_float4(-0.5f * conic_c, op, depth, 0.0f);
            g4u[s*3+2] = make_float4(cols[g*3+0], cols[g*3+1], cols[g*3+2], 0.0f);
            sdep[s]  = depth;
            sorig[s] = g;
        }
    }
    __syncthreads();
    const int n = s_n;

    // ---- stable rank permutation by (depth, orig): rank2slot ----
    for (int t = tid; t < n; t += 256) {
        const float d = sdep[t];
        const int   o = sorig[t];
        int rank = 0;
        for (int j = 0; j < n; ++j) {
            const float dj = sdep[j];
            rank += (dj < d) || (dj == d && sorig[j] < o);
        }
        rank2slot[rank] = t;
    }
    __syncthreads();
    if (tid == 0) rank2slot[n] = (n > 0) ? rank2slot[n - 1] : 0;
    __syncthreads();

    // ---- wave wv blends depth-quarter [beg, end) for its 64 pixels ----
    const int beg = (n * wv) >> 2;
    const int end = (n * (wv + 1)) >> 2;
    const float fx = (float)(xbase + lane);
    float T = 1.0f, ar = 0.f, ag = 0.f, ab = 0.f, ad = 0.f;

    if (end > beg) {
        int slot = rank2slot[beg];
        float4 h  = g4u[slot*3+0];
        float4 mm = g4u[slot*3+1];
        float4 cl = g4u[slot*3+2];
        for (int t = beg; t < end; ++t) {
            const int sn = rank2slot[t + 1];
            const float4 hn  = g4u[sn*3+0];
            const float4 mmn = g4u[sn*3+1];
            const float4 cln = g4u[sn*3+2];

            const float dx = h.z - fx;
            const float dy = h.x - fy;
            const float pw = fmaf(h.w, dx*dx, fmaf(mm.x, dy*dy, h.y * dx * dy));
            const float alpha = fminf(0.99f, mm.y * __expf(pw));
            const bool keep = (pw <= 0.0f) && (alpha >= (1.0f / 255.0f));

            const float ae  = keep ? alpha : 0.0f;
            const float wgt = ae * T;
            ar = fmaf(wgt, cl.x, ar); ag = fmaf(wgt, cl.y, ag);
            ab = fmaf(wgt, cl.z, ab); ad = fmaf(wgt, mm.z, ad);
            T  = fmaf(-ae, T, T);

            h = hn; mm = mmn; cl = cln;
        }
    }

    // ---- exact 4-way combine: final = a0 + T0*(a1 + T1*(a2 + T2*a3)) ----
    if (wv > 0) {
        part[wv-1][0][lane] = ar; part[wv-1][1][lane] = ag;
        part[wv-1][2][lane] = ab; part[wv-1][3][lane] = ad;
        part[wv-1][4][lane] = T;
    }
    __syncthreads();
    if (wv == 0) {
        float fr = ar, fg = ag, fb = ab, fd = ad, fT = T;
        #pragma unroll
        for (int s = 0; s < 3; ++s) {
            fr = fmaf(fT, part[s][0][lane], fr);
            fg = fmaf(fT, part[s][1][lane], fg);
            fb = fmaf(fT, part[s][2][lane], fb);
            fd = fmaf(fT, part[s][3][lane], fd);
            fT *= part[s][4][lane];
        }
        const int pix = row * W + xbase + lane;
        out[COLOR_OFF + 0*65536 + pix] = fr + fT * bg[0];
        out[COLOR_OFF + 1*65536 + pix] = fg + fT * bg[1];
        out[COLOR_OFF + 2*65536 + pix] = fb + fT * bg[2];
        out[DEPTH_OFF + pix]           = fd;
        out[OPAC_OFF  + pix]           = 1.0f - fT;
    }

    // ---- exact n_touched for gaussian `bid` (blocks 0..511 only) ----
    if (bid < P) {
        const float4 r0 = ntrec[0], r1 = ntrec[1];
        const float pxg = r0.x, pyg = r0.y, pa = r0.z, pb = r0.w;
        const float pc = r1.x, opg = r1.y, rx2 = r1.z, ry2 = r1.w;
        int cc2 = 0;
        if (ry2 > 0.0f && rx2 > 0.0f) {
            const float ry = sqrtf(ry2), rx = sqrtf(rx2);
            const int y0 = max(0, (int)ceilf(pyg - ry));
            const int y1 = min(H - 1, (int)floorf(pyg + ry));
            const int x0 = max(0, (int)ceilf(pxg - rx));
            const int x1 = min(W - 1, (int)floorf(pxg + rx));
            const int xx = x0 + tid;
            if (xx <= x1 && y0 <= y1) {
                const float dx = (float)xx - pxg;
                const float padx2 = pa * dx * dx;
                for (int yy = y0; yy <= y1; ++yy) {
                    const float dy = (float)yy - pyg;
                    const float pw = fmaf(pc, dy*dy, fmaf(pb, dx*dy, padx2));
                    const float alpha = fminf(0.99f, opg * __expf(pw));
                    cc2 += (pw <= 0.0f) && (alpha >= (1.0f / 255.0f));
                }
            }
        }
        #pragma unroll
        for (int off = 32; off; off >>= 1) cc2 += __shfl_down(cc2, off);
        if (lane == 0 && cc2) atomicAdd(&s_cnt, cc2);
        __syncthreads();
        if (tid == 0) out[NT_OFF + bid] = (float)s_cnt;
    }
}

extern "C" void kernel_launch(void* const* d_in, const int* in_sizes, int n_in,
                              void* d_out, int out_size, void* d_ws, size_t ws_size,
                              hipStream_t stream) {
    const float* means3D = (const float*)d_in[0];
    const float* scales  = (const float*)d_in[1];
    const float* rots    = (const float*)d_in[2];
    const float* opacs   = (const float*)d_in[3];
    const float* cols    = (const float*)d_in[4];
    const float* vm      = (const float*)d_in[5];
    const float* pm      = (const float*)d_in[6];
    const float* bg      = (const float*)d_in[8];
    float* out = (float*)d_out;

    fused_q_kernel<<<4 * H, 256, 0, stream>>>(means3D, scales, rots, opacs,
                                              cols, vm, pm, bg, out);
}

// Round 11
// 17.178 us; speedup vs baseline: 1.5376x; 1.1973x over previous
//
#include <hip/hip_runtime.h>

constexpr int   P     = 512;
constexpr int   W     = 256;
constexpr int   H     = 256;
constexpr float FXc   = 256.0f;
constexpr float FYc   = 256.0f;
constexpr float NEARc = 0.2f;
constexpr float BLUR  = 0.3f;
constexpr float LIMX  = 0.65f;
constexpr float LIMY  = 0.65f;

// d_out layout (floats)
constexpr int COLOR_OFF = 0;
constexpr int RADII_OFF = 196608;
constexpr int DEPTH_OFF = 197120;
constexpr int OPAC_OFF  = 262656;
constexpr int NT_OFF    = 328192;

struct PrepR {
    float px, py, pa, pb, pc, opv, depth;
    float rr2, xr2;          // exact cull radii^2 (y-extent / x-extent)
    float a, c, det, L;
    bool  valid;
};

__device__ __forceinline__ PrepR full_prep(
    int g,
    const float* __restrict__ means3D, const float* __restrict__ scales,
    const float* __restrict__ rots,    const float* __restrict__ opacs,
    const float* __restrict__ vm,      const float* __restrict__ pm)
{
    PrepR o;
    const float mx = means3D[g*3+0], my = means3D[g*3+1], mz = means3D[g*3+2];

    const float pv0 = vm[0]*mx + vm[1]*my + vm[2]*mz  + vm[3];
    const float pv1 = vm[4]*mx + vm[5]*my + vm[6]*mz  + vm[7];
    const float pv2 = vm[8]*mx + vm[9]*my + vm[10]*mz + vm[11];
    const float depth = pv2;

    const float ph0 = pm[0]*mx  + pm[1]*my  + pm[2]*mz  + pm[3];
    const float ph1 = pm[4]*mx  + pm[5]*my  + pm[6]*mz  + pm[7];
    const float ph3 = pm[12]*mx + pm[13]*my + pm[14]*mz + pm[15];
    const float pwn = 1.0f / (ph3 + 1e-7f);
    const float pp0 = ph0 * pwn, pp1 = ph1 * pwn;

    float q0 = rots[g*4+0], q1 = rots[g*4+1], q2 = rots[g*4+2], q3 = rots[g*4+3];
    const float qinv = 1.0f / sqrtf(q0*q0 + q1*q1 + q2*q2 + q3*q3);
    q0 *= qinv; q1 *= qinv; q2 *= qinv; q3 *= qinv;
    const float r = q0, x = q1, y = q2, z = q3;
    const float R00 = 1.f - 2.f*(y*y + z*z), R01 = 2.f*(x*y - r*z), R02 = 2.f*(x*z + r*y);
    const float R10 = 2.f*(x*y + r*z), R11 = 1.f - 2.f*(x*x + z*z), R12 = 2.f*(y*z - r*x);
    const float R20 = 2.f*(x*z - r*y), R21 = 2.f*(y*z + r*x), R22 = 1.f - 2.f*(x*x + y*y);

    const float s0 = scales[g*3+0], s1 = scales[g*3+1], s2 = scales[g*3+2];
    const float M00 = R00*s0, M01 = R01*s1, M02 = R02*s2;
    const float M10 = R10*s0, M11 = R11*s1, M12 = R12*s2;
    const float M20 = R20*s0, M21 = R21*s1, M22 = R22*s2;
    const float c00 = M00*M00 + M01*M01 + M02*M02;
    const float c01 = M00*M10 + M01*M11 + M02*M12;
    const float c02 = M00*M20 + M01*M21 + M02*M22;
    const float c11 = M10*M10 + M11*M11 + M12*M12;
    const float c12 = M10*M20 + M11*M21 + M12*M22;
    const float c22 = M20*M20 + M21*M21 + M22*M22;

    const float tz  = (fabsf(depth) < 1e-6f) ? 1e-6f : depth;
    const float txc = fminf(fmaxf(pv0 / tz, -LIMX), LIMX) * tz;
    const float tyc = fminf(fmaxf(pv1 / tz, -LIMY), LIMY) * tz;

    const float J00 = FXc / tz, J02 = -FXc * txc / (tz*tz);
    const float J11 = FYc / tz, J12 = -FYc * tyc / (tz*tz);

    const float T00 = J00*vm[0] + J02*vm[8];
    const float T01 = J00*vm[1] + J02*vm[9];
    const float T02 = J00*vm[2] + J02*vm[10];
    const float T10 = J11*vm[4] + J12*vm[8];
    const float T11 = J11*vm[5] + J12*vm[9];
    const float T12 = J11*vm[6] + J12*vm[10];

    const float V00 = T00*c00 + T01*c01 + T02*c02;
    const float V01 = T00*c01 + T01*c11 + T02*c12;
    const float V02 = T00*c02 + T01*c12 + T02*c22;
    const float V10 = T10*c00 + T11*c01 + T12*c02;
    const float V11 = T10*c01 + T11*c11 + T12*c12;
    const float V12 = T10*c02 + T11*c12 + T12*c22;

    const float a = V00*T00 + V01*T01 + V02*T02 + BLUR;
    const float b = V00*T10 + V01*T11 + V02*T12;
    const float c = V10*T10 + V11*T11 + V12*T12 + BLUR;
    const float det = a*c - b*b;

    const bool  valid = (depth > NEARc) && (det > 0.0f);
    const float det_s = valid ? det : 1.0f;

    o.pa = -0.5f * ( c / det_s);      // power = pa*dx^2 + pb*dx*dy + pc*dy^2
    o.pb = -(-b / det_s) * -1.0f;     // = -conic_b
    o.pb = (b / det_s);               // -conic_b = b/det
    o.pc = -0.5f * ( a / det_s);
    o.opv = opacs[g];
    o.depth = depth;
    const float L = logf(255.0f * o.opv);
    o.L = L;
    o.rr2 = valid ? (2.0f * c * L) * 1.0001f + 1e-4f : -1.0f;
    o.xr2 = valid ? (2.0f * a * L) * 1.0001f + 1e-4f : -1.0f;
    o.px = ((pp0 + 1.0f) * (float)W - 1.0f) * 0.5f;
    o.py = ((pp1 + 1.0f) * (float)H - 1.0f) * 0.5f;
    o.a = a; o.c = c; o.det = det;
    o.valid = valid;
    return o;
}

// 1024 blocks: b = (row = b>>2, xq = b&3) covers 64 pixels; 4 blocks/CU.
// Two-phase prep: cheap provable bound-cull + compaction, full prep only for
// candidates. 4 waves = 4 depth-quarters, rank permutation, prefetched blend,
// exact 4-way combine. n_touched[bid] (blocks 0..511) via closed-form per-row
// ellipse lattice counting (keep <=> alpha>=1/255 <=> power>=-L, conic PD).
__global__ __launch_bounds__(256, 4) void fused_q_kernel(
    const float* __restrict__ means3D, const float* __restrict__ scales,
    const float* __restrict__ rots,    const float* __restrict__ opacs,
    const float* __restrict__ cols,    const float* __restrict__ vm,
    const float* __restrict__ pm,      const float* __restrict__ bg,
    float* __restrict__ out)
{
    __shared__ float4 g4u[P * 3];
    __shared__ float  sdep[P];
    __shared__ int    sorig[P];
    __shared__ int    cand[P];
    __shared__ int    rank2slot[P + 1];
    __shared__ float  part[3][5][64];
    __shared__ float4 ntrec[2];
    __shared__ int    s_cnt, s_n, s_ncand;

    const int tid   = threadIdx.x;
    const int bid   = blockIdx.x;
    const int row   = bid >> 2;
    const int xbase = (bid & 3) * 64;
    const int wv    = tid >> 6;
    const int lane  = tid & 63;
    const float fy  = (float)row;
    const float wx0 = (float)xbase, wx1 = (float)(xbase + 63);

    if (tid == 0) { s_n = 0; s_cnt = 0; s_ncand = 0; }
    __syncthreads();

    if (bid == 0) {
        // Full-prep path: must write radii for all 512; also own window's cull.
        #pragma unroll
        for (int k = 0; k < 2; ++k) {
            const int g = tid + k * 256;
            PrepR p = full_prep(g, means3D, scales, rots, opacs, vm, pm);
            const float mid = 0.5f * (p.a + p.c);
            const float lam = mid + sqrtf(fmaxf(mid*mid - p.det, 0.1f));
            out[RADII_OFF + g] = p.valid ? ceilf(3.0f * sqrtf(lam)) : 0.0f;
            if (g == 0) {
                ntrec[0] = make_float4(p.px, p.py, p.pa, p.pb);
                ntrec[1] = make_float4(p.pc, p.L, p.xr2, p.rr2);
            }
            const float dyv = p.py - fy;
            const float dxm = fmaxf(0.0f, fmaxf(wx0 - p.px, p.px - wx1));
            if (dyv*dyv <= p.rr2 && dxm*dxm <= p.xr2) {
                const int s = atomicAdd(&s_n, 1);
                g4u[s*3+0] = make_float4(p.py, p.pb, p.px, p.pa);
                g4u[s*3+1] = make_float4(p.pc, p.opv, p.depth, 0.0f);
                g4u[s*3+2] = make_float4(cols[g*3+0], cols[g*3+1], cols[g*3+2], 0.0f);
                sdep[s]  = p.depth;
                sorig[s] = g;
            }
        }
    } else {
        // Phase A: cheap provable bound-cull (c_true <= (FY/tz)^2*(1+lim^2)*max(s^2)+blur).
        #pragma unroll
        for (int k = 0; k < 2; ++k) {
            const int g = tid + k * 256;
            const float mx = means3D[g*3+0], my = means3D[g*3+1], mz = means3D[g*3+2];
            const float depth = vm[8]*mx + vm[9]*my + vm[10]*mz + vm[11];
            const float ph0 = pm[0]*mx  + pm[1]*my  + pm[2]*mz  + pm[3];
            const float ph1 = pm[4]*mx  + pm[5]*my  + pm[6]*mz  + pm[7];
            const float ph3 = pm[12]*mx + pm[13]*my + pm[14]*mz + pm[15];
            const float pwn = 1.0f / (ph3 + 1e-7f);
            const float px = ((ph0*pwn + 1.0f) * (float)W - 1.0f) * 0.5f;
            const float py = ((ph1*pwn + 1.0f) * (float)H - 1.0f) * 0.5f;
            const float s0 = scales[g*3+0], s1 = scales[g*3+1], s2 = scales[g*3+2];
            const float ms2 = fmaxf(s0*s0, fmaxf(s1*s1, s2*s2));
            const float L   = __logf(255.0f * opacs[g]);
            const float rtz = 1.0f / depth;                 // depth>NEAR for candidates
            const float fs  = FYc * rtz;
            const float cub = fs*fs * 1.4226f * ms2 + BLUR;
            const float rr2ub = 2.0f * cub * fmaxf(L, 0.0f) * 1.001f + 1e-3f;
            const float dyv = py - fy;
            const float dxm = fmaxf(0.0f, fmaxf(wx0 - px, px - wx1));
            if (depth > NEARc && dyv*dyv <= rr2ub && dxm*dxm <= rr2ub) {
                cand[atomicAdd(&s_ncand, 1)] = g;
            }
        }
        // Dedicated: ntrec for gaussian `bid` (blocks 1..511).
        if (tid == 255 && bid < P) {
            PrepR p = full_prep(bid, means3D, scales, rots, opacs, vm, pm);
            ntrec[0] = make_float4(p.px, p.py, p.pa, p.pb);
            ntrec[1] = make_float4(p.pc, p.L, p.xr2, p.rr2);
        }
        __syncthreads();
        const int nc = s_ncand;
        // Phase B: full prep + exact cull for candidates only.
        for (int t = tid; t < nc; t += 256) {
            const int g = cand[t];
            PrepR p = full_prep(g, means3D, scales, rots, opacs, vm, pm);
            const float dyv = p.py - fy;
            const float dxm = fmaxf(0.0f, fmaxf(wx0 - p.px, p.px - wx1));
            if (dyv*dyv <= p.rr2 && dxm*dxm <= p.xr2) {
                const int s = atomicAdd(&s_n, 1);
                g4u[s*3+0] = make_float4(p.py, p.pb, p.px, p.pa);
                g4u[s*3+1] = make_float4(p.pc, p.opv, p.depth, 0.0f);
                g4u[s*3+2] = make_float4(cols[g*3+0], cols[g*3+1], cols[g*3+2], 0.0f);
                sdep[s]  = p.depth;
                sorig[s] = g;
            }
        }
    }
    __syncthreads();
    const int n = s_n;

    // ---- stable rank permutation by (depth, orig) ----
    for (int t = tid; t < n; t += 256) {
        const float d = sdep[t];
        const int   o = sorig[t];
        int rank = 0;
        for (int j = 0; j < n; ++j) {
            const float dj = sdep[j];
            rank += (dj < d) || (dj == d && sorig[j] < o);
        }
        rank2slot[rank] = t;
    }
    __syncthreads();
    if (tid == 0) rank2slot[n] = (n > 0) ? rank2slot[n - 1] : 0;
    __syncthreads();

    // ---- wave wv blends depth-quarter [beg, end) ----
    const int beg = (n * wv) >> 2;
    const int end = (n * (wv + 1)) >> 2;
    const float fx = (float)(xbase + lane);
    float T = 1.0f, ar = 0.f, ag = 0.f, ab = 0.f, ad = 0.f;

    if (end > beg) {
        int slot = rank2slot[beg];
        float4 h  = g4u[slot*3+0];
        float4 mm = g4u[slot*3+1];
        float4 cl = g4u[slot*3+2];
        for (int t = beg; t < end; ++t) {
            const int sn = rank2slot[t + 1];
            const float4 hn  = g4u[sn*3+0];
            const float4 mmn = g4u[sn*3+1];
            const float4 cln = g4u[sn*3+2];

            const float dx = h.z - fx;
            const float dy = h.x - fy;
            const float pw = fmaf(h.w, dx*dx, fmaf(mm.x, dy*dy, h.y * dx * dy));
            const float alpha = fminf(0.99f, mm.y * __expf(pw));
            const bool keep = (pw <= 0.0f) && (alpha >= (1.0f / 255.0f));

            const float ae  = keep ? alpha : 0.0f;
            const float wgt = ae * T;
            ar = fmaf(wgt, cl.x, ar); ag = fmaf(wgt, cl.y, ag);
            ab = fmaf(wgt, cl.z, ab); ad = fmaf(wgt, mm.z, ad);
            T  = fmaf(-ae, T, T);

            h = hn; mm = mmn; cl = cln;
        }
    }

    // ---- exact 4-way combine ----
    if (wv > 0) {
        part[wv-1][0][lane] = ar; part[wv-1][1][lane] = ag;
        part[wv-1][2][lane] = ab; part[wv-1][3][lane] = ad;
        part[wv-1][4][lane] = T;
    }
    __syncthreads();
    if (wv == 0) {
        float fr = ar, fg = ag, fb = ab, fd = ad, fT = T;
        #pragma unroll
        for (int s = 0; s < 3; ++s) {
            fr = fmaf(fT, part[s][0][lane], fr);
            fg = fmaf(fT, part[s][1][lane], fg);
            fb = fmaf(fT, part[s][2][lane], fb);
            fd = fmaf(fT, part[s][3][lane], fd);
            fT *= part[s][4][lane];
        }
        const int pix = row * W + xbase + lane;
        out[COLOR_OFF + 0*65536 + pix] = fr + fT * bg[0];
        out[COLOR_OFF + 1*65536 + pix] = fg + fT * bg[1];
        out[COLOR_OFF + 2*65536 + pix] = fb + fT * bg[2];
        out[DEPTH_OFF + pix]           = fd;
        out[OPAC_OFF  + pix]           = 1.0f - fT;
    }

    // ---- n_touched[bid] via closed-form per-row ellipse count ----
    if (bid < P) {
        const float4 r0 = ntrec[0], r1 = ntrec[1];
        const float pxg = r0.x, pyg = r0.y, pa = r0.z, pb = r0.w;
        const float pc = r1.x, L = r1.y, ry2 = r1.w;
        int cc2 = 0;
        if (ry2 > 0.0f) {
            const float ry = sqrtf(ry2);
            const int y0 = max(0, (int)ceilf(pyg - ry));
            const int y1 = min(H - 1, (int)floorf(pyg + ry));
            const int yy = y0 + tid;
            if (yy <= y1) {
                const float dy = (float)yy - pyg;
                const float B = pb * dy;
                const float C = fmaf(pc, dy*dy, L);
                const float disc = fmaf(B, B, -4.0f * pa * C);
                if (disc > 0.0f) {
                    const float sd = sqrtf(disc);
                    const float inv2A = 0.5f / pa;          // negative
                    const float ra = (-B + sd) * inv2A;
                    const float rb = (-B - sd) * inv2A;
                    const float lo = pxg + fminf(ra, rb);
                    const float hi = pxg + fmaxf(ra, rb);
                    const float xlo = fmaxf(ceilf(lo), 0.0f);
                    const float xhi = fminf(floorf(hi), 255.0f);
                    cc2 = max(0, (int)(xhi - xlo) + 1);
                }
            }
        }
        #pragma unroll
        for (int off = 32; off; off >>= 1) cc2 += __shfl_down(cc2, off);
        if (lane == 0 && cc2) atomicAdd(&s_cnt, cc2);
        __syncthreads();
        if (tid == 0) out[NT_OFF + bid] = (float)s_cnt;
    }
}

extern "C" void kernel_launch(void* const* d_in, const int* in_sizes, int n_in,
                              void* d_out, int out_size, void* d_ws, size_t ws_size,
                              hipStream_t stream) {
    const float* means3D = (const float*)d_in[0];
    const float* scales  = (const float*)d_in[1];
    const float* rots    = (const float*)d_in[2];
    const float* opacs   = (const float*)d_in[3];
    const float* cols    = (const float*)d_in[4];
    const float* vm      = (const float*)d_in[5];
    const float* pm      = (const float*)d_in[6];
    const float* bg      = (const float*)d_in[8];
    float* out = (float*)d_out;

    fused_q_kernel<<<4 * H, 256, 0, stream>>>(means3D, scales, rots, opacs,
                                              cols, vm, pm, bg, out);
}

// Round 12
// 16.615 us; speedup vs baseline: 1.5896x; 1.0338x over previous
//
#include <hip/hip_runtime.h>

constexpr int   P     = 512;
constexpr int   W     = 256;
constexpr int   H     = 256;
constexpr float FXc   = 256.0f;
constexpr float FYc   = 256.0f;
constexpr float NEARc = 0.2f;
constexpr float BLUR  = 0.3f;
constexpr float LIMX  = 0.65f;
constexpr float LIMY  = 0.65f;

// d_out layout (floats)
constexpr int COLOR_OFF = 0;
constexpr int RADII_OFF = 196608;
constexpr int DEPTH_OFF = 197120;
constexpr int OPAC_OFF  = 262656;
constexpr int NT_OFF    = 328192;

struct PrepR {
    float px, py, pa, pb, pc, opv, depth;
    float rr2, xr2;          // exact cull radii^2 (y-extent / x-extent)
    float a, c, det, L;
    bool  valid;
};

__device__ __forceinline__ PrepR full_prep(
    int g,
    const float* __restrict__ means3D, const float* __restrict__ scales,
    const float* __restrict__ rots,    const float* __restrict__ opacs,
    const float* __restrict__ vm,      const float* __restrict__ pm)
{
    PrepR o;
    const float mx = means3D[g*3+0], my = means3D[g*3+1], mz = means3D[g*3+2];

    const float pv0 = vm[0]*mx + vm[1]*my + vm[2]*mz  + vm[3];
    const float pv1 = vm[4]*mx + vm[5]*my + vm[6]*mz  + vm[7];
    const float pv2 = vm[8]*mx + vm[9]*my + vm[10]*mz + vm[11];
    const float depth = pv2;

    const float ph0 = pm[0]*mx  + pm[1]*my  + pm[2]*mz  + pm[3];
    const float ph1 = pm[4]*mx  + pm[5]*my  + pm[6]*mz  + pm[7];
    const float ph3 = pm[12]*mx + pm[13]*my + pm[14]*mz + pm[15];
    const float pwn = 1.0f / (ph3 + 1e-7f);
    const float pp0 = ph0 * pwn, pp1 = ph1 * pwn;

    float q0 = rots[g*4+0], q1 = rots[g*4+1], q2 = rots[g*4+2], q3 = rots[g*4+3];
    const float qinv = 1.0f / sqrtf(q0*q0 + q1*q1 + q2*q2 + q3*q3);
    q0 *= qinv; q1 *= qinv; q2 *= qinv; q3 *= qinv;
    const float r = q0, x = q1, y = q2, z = q3;
    const float R00 = 1.f - 2.f*(y*y + z*z), R01 = 2.f*(x*y - r*z), R02 = 2.f*(x*z + r*y);
    const float R10 = 2.f*(x*y + r*z), R11 = 1.f - 2.f*(x*x + z*z), R12 = 2.f*(y*z - r*x);
    const float R20 = 2.f*(x*z - r*y), R21 = 2.f*(y*z + r*x), R22 = 1.f - 2.f*(x*x + y*y);

    const float s0 = scales[g*3+0], s1 = scales[g*3+1], s2 = scales[g*3+2];
    const float M00 = R00*s0, M01 = R01*s1, M02 = R02*s2;
    const float M10 = R10*s0, M11 = R11*s1, M12 = R12*s2;
    const float M20 = R20*s0, M21 = R21*s1, M22 = R22*s2;
    const float c00 = M00*M00 + M01*M01 + M02*M02;
    const float c01 = M00*M10 + M01*M11 + M02*M12;
    const float c02 = M00*M20 + M01*M21 + M02*M22;
    const float c11 = M10*M10 + M11*M11 + M12*M12;
    const float c12 = M10*M20 + M11*M21 + M12*M22;
    const float c22 = M20*M20 + M21*M21 + M22*M22;

    const float tz  = (fabsf(depth) < 1e-6f) ? 1e-6f : depth;
    const float txc = fminf(fmaxf(pv0 / tz, -LIMX), LIMX) * tz;
    const float tyc = fminf(fmaxf(pv1 / tz, -LIMY), LIMY) * tz;

    const float J00 = FXc / tz, J02 = -FXc * txc / (tz*tz);
    const float J11 = FYc / tz, J12 = -FYc * tyc / (tz*tz);

    const float T00 = J00*vm[0] + J02*vm[8];
    const float T01 = J00*vm[1] + J02*vm[9];
    const float T02 = J00*vm[2] + J02*vm[10];
    const float T10 = J11*vm[4] + J12*vm[8];
    const float T11 = J11*vm[5] + J12*vm[9];
    const float T12 = J11*vm[6] + J12*vm[10];

    const float V00 = T00*c00 + T01*c01 + T02*c02;
    const float V01 = T00*c01 + T01*c11 + T02*c12;
    const float V02 = T00*c02 + T01*c12 + T02*c22;
    const float V10 = T10*c00 + T11*c01 + T12*c02;
    const float V11 = T10*c01 + T11*c11 + T12*c12;
    const float V12 = T10*c02 + T11*c12 + T12*c22;

    const float a = V00*T00 + V01*T01 + V02*T02 + BLUR;
    const float b = V00*T10 + V01*T11 + V02*T12;
    const float c = V10*T10 + V11*T11 + V12*T12 + BLUR;
    const float det = a*c - b*b;

    const bool  valid = (depth > NEARc) && (det > 0.0f);
    const float det_s = valid ? det : 1.0f;

    o.pa = -0.5f * (c / det_s);       // power = pa*dx^2 + pb*dx*dy + pc*dy^2
    o.pb = (b / det_s);               // = -conic_b
    o.pc = -0.5f * (a / det_s);
    o.opv = opacs[g];
    o.depth = depth;
    const float L = logf(255.0f * o.opv);
    o.L = L;
    o.rr2 = valid ? (2.0f * c * L) * 1.0001f + 1e-4f : -1.0f;
    o.xr2 = valid ? (2.0f * a * L) * 1.0001f + 1e-4f : -1.0f;
    o.px = ((pp0 + 1.0f) * (float)W - 1.0f) * 0.5f;
    o.py = ((pp1 + 1.0f) * (float)H - 1.0f) * 0.5f;
    o.a = a; o.c = c; o.det = det;
    o.valid = valid;
    return o;
}

// 1024 blocks: b = (row = b>>2, xq = b&3) covers 64 pixels; 4 blocks/CU.
// Uniform path for ALL blocks: Phase A cheap provable bound-cull (plus forced
// inclusion of gaussian `bid` for blocks 0..511), Phase B full prep of the
// ~nc candidates only — the thread prepping g==bid also writes radii[bid] and
// this block's ntrec (distributes per-gaussian output work across 512 blocks;
// no serial dedicated prep, no block-0 outlier). 4 waves = 4 depth-quarters,
// rank permutation, prefetched blend, exact 4-way combine. n_touched[bid]
// via closed-form per-row ellipse lattice counting.
__global__ __launch_bounds__(256, 4) void fused_q_kernel(
    const float* __restrict__ means3D, const float* __restrict__ scales,
    const float* __restrict__ rots,    const float* __restrict__ opacs,
    const float* __restrict__ cols,    const float* __restrict__ vm,
    const float* __restrict__ pm,      const float* __restrict__ bg,
    float* __restrict__ out)
{
    __shared__ float4 g4u[P * 3];
    __shared__ float  sdep[P];
    __shared__ int    sorig[P];
    __shared__ int    cand[P];
    __shared__ int    rank2slot[P + 1];
    __shared__ float  part[3][5][64];
    __shared__ float4 ntrec[2];
    __shared__ int    s_cnt, s_n, s_ncand;

    const int tid   = threadIdx.x;
    const int bid   = blockIdx.x;
    const int row   = bid >> 2;
    const int xbase = (bid & 3) * 64;
    const int wv    = tid >> 6;
    const int lane  = tid & 63;
    const float fy  = (float)row;
    const float wx0 = (float)xbase, wx1 = (float)(xbase + 63);

    if (tid == 0) { s_n = 0; s_cnt = 0; s_ncand = 0; }
    __syncthreads();

    // ---- Phase A: cheap provable bound-cull + forced bid inclusion ----
    // c_true <= (FY/tz)^2 * (1+lim^2) * max(s^2) + blur  (1+0.65^2 = 1.4225)
    #pragma unroll
    for (int k = 0; k < 2; ++k) {
        const int g = tid + k * 256;
        const float mx = means3D[g*3+0], my = means3D[g*3+1], mz = means3D[g*3+2];
        const float depth = vm[8]*mx + vm[9]*my + vm[10]*mz + vm[11];
        const float ph0 = pm[0]*mx  + pm[1]*my  + pm[2]*mz  + pm[3];
        const float ph1 = pm[4]*mx  + pm[5]*my  + pm[6]*mz  + pm[7];
        const float ph3 = pm[12]*mx + pm[13]*my + pm[14]*mz + pm[15];
        const float pwn = 1.0f / (ph3 + 1e-7f);
        const float px = ((ph0*pwn + 1.0f) * (float)W - 1.0f) * 0.5f;
        const float py = ((ph1*pwn + 1.0f) * (float)H - 1.0f) * 0.5f;
        const float s0 = scales[g*3+0], s1 = scales[g*3+1], s2 = scales[g*3+2];
        const float ms2 = fmaxf(s0*s0, fmaxf(s1*s1, s2*s2));
        const float L   = __logf(255.0f * opacs[g]);
        const float rtz = 1.0f / depth;               // only used when depth>NEAR
        const float fs  = FYc * rtz;
        const float cub = fs*fs * 1.4226f * ms2 + BLUR;
        const float rr2ub = 2.0f * cub * fmaxf(L, 0.0f) * 1.001f + 1e-3f;
        const float dyv = py - fy;
        const float dxm = fmaxf(0.0f, fmaxf(wx0 - px, px - wx1));
        const bool  pass = depth > NEARc && dyv*dyv <= rr2ub && dxm*dxm <= rr2ub;
        if (pass || g == bid) {
            cand[atomicAdd(&s_ncand, 1)] = g;
        }
    }
    __syncthreads();
    const int nc = s_ncand;

    // ---- Phase B: full prep for candidates; owner thread of g==bid also
    //      writes radii[bid] and this block's ntrec ----
    for (int t = tid; t < nc; t += 256) {
        const int g = cand[t];
        PrepR p = full_prep(g, means3D, scales, rots, opacs, vm, pm);
        if (g == bid) {
            const float mid = 0.5f * (p.a + p.c);
            const float lam = mid + sqrtf(fmaxf(mid*mid - p.det, 0.1f));
            out[RADII_OFF + g] = p.valid ? ceilf(3.0f * sqrtf(lam)) : 0.0f;
            ntrec[0] = make_float4(p.px, p.py, p.pa, p.pb);
            ntrec[1] = make_float4(p.pc, p.L, p.xr2, p.rr2);
        }
        const float dyv = p.py - fy;
        const float dxm = fmaxf(0.0f, fmaxf(wx0 - p.px, p.px - wx1));
        if (dyv*dyv <= p.rr2 && dxm*dxm <= p.xr2) {
            const int s = atomicAdd(&s_n, 1);
            g4u[s*3+0] = make_float4(p.py, p.pb, p.px, p.pa);
            g4u[s*3+1] = make_float4(p.pc, p.opv, p.depth, 0.0f);
            g4u[s*3+2] = make_float4(cols[g*3+0], cols[g*3+1], cols[g*3+2], 0.0f);
            sdep[s]  = p.depth;
            sorig[s] = g;
        }
    }
    __syncthreads();
    const int n = s_n;

    // ---- stable rank permutation by (depth, orig) ----
    for (int t = tid; t < n; t += 256) {
        const float d = sdep[t];
        const int   o = sorig[t];
        int rank = 0;
        for (int j = 0; j < n; ++j) {
            const float dj = sdep[j];
            rank += (dj < d) || (dj == d && sorig[j] < o);
        }
        rank2slot[rank] = t;
    }
    __syncthreads();
    if (tid == 0) rank2slot[n] = (n > 0) ? rank2slot[n - 1] : 0;
    __syncthreads();

    // ---- wave wv blends depth-quarter [beg, end) ----
    const int beg = (n * wv) >> 2;
    const int end = (n * (wv + 1)) >> 2;
    const float fx = (float)(xbase + lane);
    float T = 1.0f, ar = 0.f, ag = 0.f, ab = 0.f, ad = 0.f;

    if (end > beg) {
        int slot = rank2slot[beg];
        float4 h  = g4u[slot*3+0];
        float4 mm = g4u[slot*3+1];
        float4 cl = g4u[slot*3+2];
        for (int t = beg; t < end; ++t) {
            const int sn = rank2slot[t + 1];
            const float4 hn  = g4u[sn*3+0];
            const float4 mmn = g4u[sn*3+1];
            const float4 cln = g4u[sn*3+2];

            const float dx = h.z - fx;
            const float dy = h.x - fy;
            const float pw = fmaf(h.w, dx*dx, fmaf(mm.x, dy*dy, h.y * dx * dy));
            const float alpha = fminf(0.99f, mm.y * __expf(pw));
            const bool keep = (pw <= 0.0f) && (alpha >= (1.0f / 255.0f));

            const float ae  = keep ? alpha : 0.0f;
            const float wgt = ae * T;
            ar = fmaf(wgt, cl.x, ar); ag = fmaf(wgt, cl.y, ag);
            ab = fmaf(wgt, cl.z, ab); ad = fmaf(wgt, mm.z, ad);
            T  = fmaf(-ae, T, T);

            h = hn; mm = mmn; cl = cln;
        }
    }

    // ---- exact 4-way combine ----
    if (wv > 0) {
        part[wv-1][0][lane] = ar; part[wv-1][1][lane] = ag;
        part[wv-1][2][lane] = ab; part[wv-1][3][lane] = ad;
        part[wv-1][4][lane] = T;
    }
    __syncthreads();
    if (wv == 0) {
        float fr = ar, fg = ag, fb = ab, fd = ad, fT = T;
        #pragma unroll
        for (int s = 0; s < 3; ++s) {
            fr = fmaf(fT, part[s][0][lane], fr);
            fg = fmaf(fT, part[s][1][lane], fg);
            fb = fmaf(fT, part[s][2][lane], fb);
            fd = fmaf(fT, part[s][3][lane], fd);
            fT *= part[s][4][lane];
        }
        const int pix = row * W + xbase + lane;
        out[COLOR_OFF + 0*65536 + pix] = fr + fT * bg[0];
        out[COLOR_OFF + 1*65536 + pix] = fg + fT * bg[1];
        out[COLOR_OFF + 2*65536 + pix] = fb + fT * bg[2];
        out[DEPTH_OFF + pix]           = fd;
        out[OPAC_OFF  + pix]           = 1.0f - fT;
    }

    // ---- n_touched[bid] via closed-form per-row ellipse count ----
    if (bid < P) {
        const float4 r0 = ntrec[0], r1 = ntrec[1];
        const float pxg = r0.x, pyg = r0.y, pa = r0.z, pb = r0.w;
        const float pc = r1.x, L = r1.y, ry2 = r1.w;
        int cc2 = 0;
        if (ry2 > 0.0f) {
            const float ry = sqrtf(ry2);
            const int y0 = max(0, (int)ceilf(pyg - ry));
            const int y1 = min(H - 1, (int)floorf(pyg + ry));
            const int yy = y0 + tid;
            if (yy <= y1) {
                const float dy = (float)yy - pyg;
                const float B = pb * dy;
                const float C = fmaf(pc, dy*dy, L);
                const float disc = fmaf(B, B, -4.0f * pa * C);
                if (disc > 0.0f) {
                    const float sd = sqrtf(disc);
                    const float inv2A = 0.5f / pa;          // negative
                    const float ra = (-B + sd) * inv2A;
                    const float rb = (-B - sd) * inv2A;
                    const float lo = pxg + fminf(ra, rb);
                    const float hi = pxg + fmaxf(ra, rb);
                    const float xlo = fmaxf(ceilf(lo), 0.0f);
                    const float xhi = fminf(floorf(hi), 255.0f);
                    cc2 = max(0, (int)(xhi - xlo) + 1);
                }
            }
        }
        #pragma unroll
        for (int off = 32; off; off >>= 1) cc2 += __shfl_down(cc2, off);
        if (lane == 0 && cc2) atomicAdd(&s_cnt, cc2);
        __syncthreads();
        if (tid == 0) out[NT_OFF + bid] = (float)s_cnt;
    }
}

extern "C" void kernel_launch(void* const* d_in, const int* in_sizes, int n_in,
                              void* d_out, int out_size, void* d_ws, size_t ws_size,
                              hipStream_t stream) {
    const float* means3D = (const float*)d_in[0];
    const float* scales  = (const float*)d_in[1];
    const float* rots    = (const float*)d_in[2];
    const float* opacs   = (const float*)d_in[3];
    const float* cols    = (const float*)d_in[4];
    const float* vm      = (const float*)d_in[5];
    const float* pm      = (const float*)d_in[6];
    const float* bg      = (const float*)d_in[8];
    float* out = (float*)d_out;

    fused_q_kernel<<<4 * H, 256, 0, stream>>>(means3D, scales, rots, opacs,
                                              cols, vm, pm, bg, out);
}